// Round 7
// baseline (58851.752 us; speedup 1.0000x reference)
//
#include <hip/hip_runtime.h>

#define T_STEPS 2048
#define NBATCH  32
#define IN_DIM  64
#define RES     1024
#define LEAKF   0.3f
#define NGRP    4    // batch groups (8 batches each)
#define BPG     16   // producer blocks per group (was 64) — rendezvous degree

typedef unsigned int u32;
typedef unsigned long long u64cp;

// ---------------------------------------------------------------------------
// Round 7: same PROVEN sync protocol as R6, restructured decomposition.
// Evidence: R1/R2/R6 all land at ~10.5us/step regardless of protocol shape
// (flag array / staged / single counter + s_sleep) -> the cost is the
// rendezvous STRUCTURE (64 producers, 256 blocks, 1 wave/SIMD), not the
// encoding of readiness. This round: 64 blocks x 1024 threads; 4 groups x
// 16 producers; block owns 64 cols x 8 batches. Degree 64->16, 4 waves/SIMD
// (latency overlap at last), broadcast LDS reads, pad-free pl.
// Per-thread inner loop and all reduction orders are byte-identical to the
// verified kernel (w[64] regs, 8 accs, k-chunks of 64, q=0..15 ascending).
// ---------------------------------------------------------------------------
__global__ __launch_bounds__(1024) void esn_persist(
    const float* __restrict__ inp,   // [32][2048][64]
    const float* __restrict__ Win,   // [64][1024]
    const float* __restrict__ Wres,  // [1024][1024]
    float* __restrict__ out,         // [32][2048][1024]
    float* __restrict__ sC,          // ws+1KB: [4][2][1024][8] compact state
    u32* __restrict__ cnts)          // ws: 4 counters, 64 u32 (256B) apart
{
    const int tid   = threadIdx.x;
    const int c_loc = tid & 63;            // column within block
    const int ks    = tid >> 6;            // 0..15 : k-chunk [64*ks, 64*ks+64)
    const int g     = blockIdx.x & 3;      // batch group
    const int rank  = blockIdx.x >> 2;     // 0..15 producer rank in group
    const int c0    = rank * 64;
    const int b0    = g * 8;
    const int c     = c0 + c_loc;

    // Wres slice in registers: w[j] = Wres[ks*64+j][c]. Static indexing only.
    float w[64];
    {
        const float* wp = Wres + (size_t)(ks * 64) * RES + c;
        #pragma unroll
        for (int j = 0; j < 64; ++j) w[j] = wp[(size_t)j * RES];
    }

    // State image: row k (8 batches, 32B) at sst + k*8. Phase-C reads are
    // wave-UNIFORM (whole wave shares ks and j) -> pure broadcast, no banks.
    __shared__ __align__(16) float sst[RES * 8];   // 32 KB
    // k-partials: write pl[ks][b][c_loc] (64 consecutive floats per wave),
    // read pl[q][fb][cl] (64 consecutive floats per wave) -> conflict-free.
    __shared__ float pl[16][8][64];                // 32 KB

    u32* cnt = cnts + g * 64;              // this group's arrival counter
    float* sCb = sC + (size_t)g * 2 * RES * 8;

    // Finalize identity (tid < 512): batch lane fb = ks (0..7), column c.
    const int fb = ks;
    float s_prev = 0.f;                    // register-carried state (b0+fb, c)

    for (int t = 0; t < T_STEPS; ++t) {
        float* sCr = sCb + ((t & 1) ^ 1) * (RES * 8);  // state t-1
        float* sCw = sCb + (t & 1) * (RES * 8);        // state t

        // ---- Phase A: input projection (state-independent; overlaps wait)
        float x = 0.f;
        if (tid < 512) {
            const float* inb = inp + ((size_t)(b0 + fb) * T_STEPS + t) * IN_DIM;
            #pragma unroll
            for (int i = 0; i < IN_DIM; i += 4) {
                const float4 v = *reinterpret_cast<const float4*>(inb + i);
                x = fmaf(v.x, Win[(size_t)(i + 0) * RES + c], x);
                x = fmaf(v.y, Win[(size_t)(i + 1) * RES + c], x);
                x = fmaf(v.z, Win[(size_t)(i + 2) * RES + c], x);
                x = fmaf(v.w, Win[(size_t)(i + 3) * RES + c], x);
            }
        }

        if (t > 0) {
            // ---- Phase B: single-thread wait for the 16 producers of t-1.
            if (tid == 0) {
                const u32 tgt = (u32)BPG * (u32)t;
                while (__hip_atomic_load(cnt, __ATOMIC_RELAXED,
                                         __HIP_MEMORY_SCOPE_AGENT) < tgt) {
                    __builtin_amdgcn_s_sleep(1);
                }
            }
            __syncthreads();

            // ---- Phase B2: cooperative stage of the 32 KB state slab.
            // 4096 u64 words; thread tid pulls words {q*1024+tid}.
            #pragma unroll
            for (int q = 0; q < 4; ++q) {
                const int mw = q * 1024 + tid;
                const u64cp v = __hip_atomic_load((const u64cp*)sCr + mw,
                                    __ATOMIC_RELAXED, __HIP_MEMORY_SCOPE_AGENT);
                reinterpret_cast<u64cp*>(sst)[mw] = v;
            }
            __syncthreads();
        }

        // ---- Phase C: acc(b) = sum over k-chunk of W[k][c]*s[k][b] (LDS bcast).
        float acc0 = 0.f, acc1 = 0.f, acc2 = 0.f, acc3 = 0.f;
        float acc4 = 0.f, acc5 = 0.f, acc6 = 0.f, acc7 = 0.f;
        if (t > 0) {
            const float* base = sst + ks * 512;   // 64 rows x 8 floats
            #pragma unroll
            for (int j = 0; j < 64; ++j) {
                const float4 sa = *reinterpret_cast<const float4*>(base + j * 8);
                const float4 sb = *reinterpret_cast<const float4*>(base + j * 8 + 4);
                const float wj = w[j];
                acc0 = fmaf(sa.x, wj, acc0);
                acc1 = fmaf(sa.y, wj, acc1);
                acc2 = fmaf(sa.z, wj, acc2);
                acc3 = fmaf(sa.w, wj, acc3);
                acc4 = fmaf(sb.x, wj, acc4);
                acc5 = fmaf(sb.y, wj, acc5);
                acc6 = fmaf(sb.z, wj, acc6);
                acc7 = fmaf(sb.w, wj, acc7);
            }
        }

        // ---- Phase D: 16-way k-reduce through LDS, then finalize.
        pl[ks][0][c_loc] = acc0;
        pl[ks][1][c_loc] = acc1;
        pl[ks][2][c_loc] = acc2;
        pl[ks][3][c_loc] = acc3;
        pl[ks][4][c_loc] = acc4;
        pl[ks][5][c_loc] = acc5;
        pl[ks][6][c_loc] = acc6;
        pl[ks][7][c_loc] = acc7;
        __syncthreads();

        if (tid < 512) {
            float sum = 0.f;
            #pragma unroll
            for (int q = 0; q < 16; ++q) sum += pl[q][fb][c_loc];

            const float nw = tanhf(x + sum);
            const float sn = fmaf(1.0f - LEAKF, s_prev, LEAKF * nw);
            s_prev = sn;

            out[((size_t)(b0 + fb) * T_STEPS + t) * RES + c] = sn;
            __hip_atomic_store(sCw + (size_t)c * 8 + fb, sn,
                               __ATOMIC_RELAXED, __HIP_MEMORY_SCOPE_AGENT);
        }
        // Barrier: every wave drains vmcnt(0) before passing -> this block's
        // 512 state stores are at the coherence point afterwards.
        __syncthreads();

        // ---- Phase E: publish completion of step t (one add per block).
        if (tid == 0)
            __hip_atomic_fetch_add(cnt, 1u, __ATOMIC_RELAXED,
                                   __HIP_MEMORY_SCOPE_AGENT);
    }
}

// ---------------------------------------------------------------------------
// Fallback: proven per-step kernel (used only if ws too small).
// ---------------------------------------------------------------------------
__global__ __launch_bounds__(256) void esn_step(
    const float* __restrict__ inp,
    const float* __restrict__ Win,
    const float* __restrict__ Wres,
    float* __restrict__ out,
    float* __restrict__ sT,
    int t)
{
    const int tid   = threadIdx.x;
    const int c_loc = tid & 15;
    const int ks    = tid >> 4;
    const int c0    = blockIdx.x * 16;
    const int b0    = blockIdx.y * 8;
    const int c     = c0 + c_loc;

    const float* sTr = sT + ((t & 1) ^ 1) * (RES * NBATCH);
    float*       sTw = sT + (t & 1) * (RES * NBATCH);

    float acc0 = 0.f, acc1 = 0.f, acc2 = 0.f, acc3 = 0.f;
    float acc4 = 0.f, acc5 = 0.f, acc6 = 0.f, acc7 = 0.f;

    if (t > 0) {
        const int kbeg = ks * 64;
        const float* wp = Wres + (size_t)kbeg * RES + c;
        const float* sp = sTr + kbeg * NBATCH + b0;
        #pragma unroll 4
        for (int j = 0; j < 64; ++j) {
            const float w = wp[(size_t)j * RES];
            const float4 sa = *reinterpret_cast<const float4*>(sp + j * NBATCH);
            const float4 sb = *reinterpret_cast<const float4*>(sp + j * NBATCH + 4);
            acc0 = fmaf(sa.x, w, acc0);
            acc1 = fmaf(sa.y, w, acc1);
            acc2 = fmaf(sa.z, w, acc2);
            acc3 = fmaf(sa.w, w, acc3);
            acc4 = fmaf(sb.x, w, acc4);
            acc5 = fmaf(sb.y, w, acc5);
            acc6 = fmaf(sb.z, w, acc6);
            acc7 = fmaf(sb.w, w, acc7);
        }
    }

    __shared__ float plf[16][8][17];
    plf[ks][0][c_loc] = acc0;
    plf[ks][1][c_loc] = acc1;
    plf[ks][2][c_loc] = acc2;
    plf[ks][3][c_loc] = acc3;
    plf[ks][4][c_loc] = acc4;
    plf[ks][5][c_loc] = acc5;
    plf[ks][6][c_loc] = acc6;
    plf[ks][7][c_loc] = acc7;
    __syncthreads();

    if (tid < 128) {
        const int b   = tid >> 4;
        const int cl  = tid & 15;
        const int cgl = c0 + cl;
        const int bgl = b0 + b;

        float sum = 0.f;
        #pragma unroll
        for (int q = 0; q < 16; ++q) sum += plf[q][b][cl];

        const float* inb = inp + ((size_t)bgl * T_STEPS + t) * IN_DIM;
        float x = 0.f;
        #pragma unroll 8
        for (int i = 0; i < IN_DIM; ++i)
            x = fmaf(inb[i], Win[(size_t)i * RES + cgl], x);

        const float nw = tanhf(x + sum);
        const float spv = (t > 0) ? sTr[cgl * NBATCH + bgl] : 0.f;
        const float sn = fmaf(1.0f - LEAKF, spv, LEAKF * nw);

        out[((size_t)bgl * T_STEPS + t) * RES + cgl] = sn;
        sTw[cgl * NBATCH + bgl] = sn;
    }
}

extern "C" void kernel_launch(void* const* d_in, const int* in_sizes, int n_in,
                              void* d_out, int out_size, void* d_ws, size_t ws_size,
                              hipStream_t stream)
{
    const float* inp  = (const float*)d_in[0];   // [32,2048,64]
    const float* Win  = (const float*)d_in[1];   // [64,1024]
    const float* Wres = (const float*)d_in[2];   // [1024,1024]
    float* out = (float*)d_out;                  // [32,2048,1024]

    const size_t cntBytes   = 1024;                                        // 4 x 256B
    const size_t stateBytes = (size_t)NGRP * 2 * RES * 8 * sizeof(float);  // 256 KB

    if (ws_size >= cntBytes + stateBytes) {
        u32*   cnts = (u32*)d_ws;
        float* sC   = (float*)((char*)d_ws + cntBytes);
        hipMemsetAsync(cnts, 0, cntBytes, stream);   // re-zeroed every replay
        hipLaunchKernelGGL(esn_persist, dim3(NGRP * BPG), dim3(1024), 0, stream,
                           inp, Win, Wres, out, sC, cnts);
        return;
    }

    // Workspace too small: proven per-step path.
    float* sT = (float*)d_ws;   // [2][1024][32]
    dim3 grid(64, 4), blk(256);
    for (int t = 0; t < T_STEPS; ++t) {
        hipLaunchKernelGGL(esn_step, grid, blk, 0, stream,
                           inp, Win, Wres, out, sT, t);
    }
}